// Round 7
// baseline (156.385 us; speedup 1.0000x reference)
//
#include <hip/hip_runtime.h>
#include <stdint.h>

#define HH 512
#define WW 512
#define NIMG 8
#define SEGS 8                 // blocks per image (row split)
#define OWNR 64                // rows owned per block
#define HALO 32                // halo rows simulated each side
#define RAD 10
#define KPP 3                  // iterations per exchange period (10*3 <= HALO-2)
#define NPER 17                // 17*3 = 51 total passes
#define WPR 16                 // u32 words per row
#define IMG_WORDS (HH*WPR)     // 8192 words per image
#define CSTR 156               // LDS col stride: 12 low guard + 128 band + 16 high guard
#define GLO 12                 // low guard rows
#define RPT 8                  // band rows per thread (128 rows / 16 groups)

__device__ inline void gstore(uint32_t* p, uint32_t v) {
    __hip_atomic_store(p, v, __ATOMIC_RELAXED, __HIP_MEMORY_SCOPE_AGENT);
}
__device__ inline uint32_t gload(const uint32_t* p) {
    return __hip_atomic_load(p, __ATOMIC_RELAXED, __HIP_MEMORY_SCOPE_AGENT);
}

// ---- Kernel 1: det bits (x1>x0) + per-BLOCK argmax key (no atomics) --------
__global__ __launch_bounds__(256) void k_det(const float* __restrict__ in,
                                             uint32_t* __restrict__ det,
                                             unsigned long long* __restrict__ keys) {
    __shared__ unsigned long long red[4];
    int tid  = blockIdx.x * 256 + threadIdx.x;
    int lane = threadIdx.x & 63;
    int wv   = threadIdx.x >> 6;
    int wave = tid >> 6;
    long long base = (long long)wave * 256;     // 4 rounds x 64 pixels
    unsigned long long best = 0;
    const float2* in2 = (const float2*)in;
    #pragma unroll
    for (int j = 0; j < 4; ++j) {
        long long p = base + j * 64 + lane;
        float2 v = in2[p];
        // round(softmax_1(v)) == 1  <=>  v.y > v.x   (exact; no expf needed)
        float d = v.y - v.x;
        int pred = (d > 0.0f);
        unsigned long long bits = __ballot(pred);
        if (lane == 0) ((unsigned long long*)det)[wave * 4 + j] = bits;
        // argmax of softmax_1 == argmax of d (sigmoid strictly monotone).
        uint32_t du = __float_as_uint(d);
        uint32_t mono = (du & 0x80000000u) ? ~du : (du | 0x80000000u);
        uint32_t pix = (uint32_t)(p & (HH * WW - 1));
        unsigned long long key = ((unsigned long long)mono << 32)
                               | (unsigned long long)(0xFFFFFFFFu - pix);
        best = key > best ? key : best;
    }
    #pragma unroll
    for (int s = 32; s > 0; s >>= 1) {
        unsigned long long o = __shfl_xor(best, s);
        best = o > best ? o : best;
    }
    if (lane == 0) red[wv] = best;
    __syncthreads();
    if (threadIdx.x == 0) {
        unsigned long long b0 = red[0], b1 = red[1], b2 = red[2], b3 = red[3];
        b0 = b0 > b1 ? b0 : b1;
        b2 = b2 > b3 ? b2 : b3;
        keys[blockIdx.x] = b0 > b2 ? b0 : b2;   // plain store, no atomics
    }
}

// ---- Kernel 2: geodesic dilation, 8 blocks/image, periodic halo exchange ---
__global__ __launch_bounds__(256) void k_grow(const uint32_t* __restrict__ det,
                                              const unsigned long long* __restrict__ keys,
                                              uint32_t* __restrict__ fin,
                                              uint32_t* __restrict__ gobj,
                                              uint32_t* __restrict__ flags) {
    __shared__ __align__(16) uint32_t hb[2][WPR * CSTR];  // ~20 KB, col-major
    __shared__ unsigned long long redk[4];
    int blk  = blockIdx.x;
    int img  = blk & 7;                  // consecutive blkIdx -> same img spread over XCDs? no:
    int seg  = blk >> 3;                 // img = blk&7 co-locates an image's segs per XCD
    int t    = threadIdx.x;
    int lane = t & 63;
    int wvid = t >> 6;
    int w    = t & 15;                   // word-in-row == lane&15 (DPP row)
    int g    = t >> 4;                   // band row-group 0..15
    int R0   = seg * OWNR;
    int gr0  = R0 - HALO + g * RPT;      // global row of this thread's first band row

    uint32_t dreg[RPT];
    const uint32_t* db = det + img * IMG_WORDS;
    #pragma unroll
    for (int k = 0; k < RPT; ++k) {
        int r = gr0 + k;
        dreg[k] = (r >= 0 && r < HH) ? db[r * WPR + w] : 0u;
    }

    // reduce this image's 256 block keys -> single argmax key
    unsigned long long kk = keys[img * 256 + t];
    #pragma unroll
    for (int s = 32; s > 0; s >>= 1) {
        unsigned long long o = __shfl_xor(kk, s);
        kk = o > kk ? o : kk;
    }
    if (lane == 0) redk[wvid] = kk;

    for (int i = t; i < 2 * WPR * CSTR; i += 256) ((uint32_t*)hb)[i] = 0;
    __syncthreads();

    unsigned long long key = redk[0];
    key = redk[1] > key ? redk[1] : key;
    key = redk[2] > key ? redk[2] : key;
    key = redk[3] > key ? redk[3] : key;
    uint32_t pix = 0xFFFFFFFFu - (uint32_t)key;
    int sr = pix >> 9, sc = pix & 511;
    uint32_t curreg[RPT];
    #pragma unroll
    for (int k = 0; k < RPT; ++k)        // sparse seed, registers only
        curreg[k] = (gr0 + k == sr && (sc >> 5) == w) ? (1u << (sc & 31)) : 0u;

    int it = 0;
    for (int per = 0; per < NPER; ++per) {
        #pragma unroll
        for (int j = 0; j < KPP; ++j, ++it) {
            uint32_t* colv = &hb[it & 1][w * CSTR];
            // ---- horizontal radius-10: DPP neighbors + u64 log-doubling ----
            uint32_t Dv[RPT];
            #pragma unroll
            for (int k = 0; k < RPT; ++k) {
                uint32_t bb = curreg[k];
                uint32_t a = (uint32_t)__builtin_amdgcn_update_dpp(
                    0, (int)bb, 0x111, 0xF, 0xF, true);   // word w-1 (0 at w==0)
                uint32_t c = (uint32_t)__builtin_amdgcn_update_dpp(
                    0, (int)bb, 0x101, 0xF, 0xF, true);   // word w+1 (0 at w==15)
                unsigned long long W = (unsigned long long)(a >> 22)
                                     | ((unsigned long long)bb << 10)
                                     | ((unsigned long long)c << 42);
                unsigned long long D = W | (W >> 1);      // [0,1]
                D |= D >> 2;                              // [0,3]
                D |= D >> 4;                              // [0,7]
                unsigned long long D7 = D;
                D |= D >> 8;                              // [0,15]
                D |= D7 >> 13;                            // | [13,20] = [0,20]
                Dv[k] = (uint32_t)D;
            }
            int r0 = g * RPT;
            *(uint4*)&colv[r0 + GLO]     = make_uint4(Dv[0], Dv[1], Dv[2], Dv[3]);
            *(uint4*)&colv[r0 + GLO + 4] = make_uint4(Dv[4], Dv[5], Dv[6], Dv[7]);
            __syncthreads();             // single barrier per iteration

            // ---- vertical 21-row OR over 28-row window ----
            uint32_t x[28];
            {
                uint2 a0 = *(const uint2*)&colv[r0 + 2];    // band rows r0-10,r0-9
                uint4 a1 = *(const uint4*)&colv[r0 + 4];    // r0-8..r0-5
                uint4 a2 = *(const uint4*)&colv[r0 + 8];    // r0-4..r0-1
                uint4 b0 = *(const uint4*)&colv[r0 + 20];   // r0+8..r0+11
                uint4 b1 = *(const uint4*)&colv[r0 + 24];   // r0+12..r0+15
                uint2 b2 = *(const uint2*)&colv[r0 + 28];   // r0+16,r0+17
                x[0] = a0.x;  x[1] = a0.y;
                x[2] = a1.x;  x[3] = a1.y;  x[4] = a1.z;  x[5] = a1.w;
                x[6] = a2.x;  x[7] = a2.y;  x[8] = a2.z;  x[9] = a2.w;
                #pragma unroll
                for (int k = 0; k < RPT; ++k) x[10 + k] = Dv[k];
                x[18] = b0.x; x[19] = b0.y; x[20] = b0.z; x[21] = b0.w;
                x[22] = b1.x; x[23] = b1.y; x[24] = b1.z; x[25] = b1.w;
                x[26] = b2.x; x[27] = b2.y;
            }
            uint32_t s[21];
            s[20] = x[20];
            #pragma unroll
            for (int i = 19; i >= 0; --i) s[i] = x[i] | s[i + 1];
            uint32_t p[28];
            p[21] = x[21];
            #pragma unroll
            for (int i = 22; i < 28; ++i) p[i] = x[i] | p[i - 1];
            curreg[0] = dreg[0] & s[0];
            #pragma unroll
            for (int k = 1; k < RPT; ++k)
                curreg[k] = dreg[k] & (s[k] | p[k + 20]);
        }
        if (per == NPER - 1) break;

        // ---- halo exchange (period-parity double-buffered canvas) ----
        uint32_t* gb = gobj + ((per & 1) * NIMG + img) * IMG_WORDS;
        if (g >= 4 && g < 12) {          // store own 64 rows
            #pragma unroll
            for (int k = 0; k < RPT; ++k)
                gstore(&gb[(gr0 + k) * WPR + w], curreg[k]);
        }
        __threadfence();
        __syncthreads();                 // all stores drained before flag
        uint32_t* fl = &flags[img * 8];
        if (t == 0)
            __hip_atomic_store(&fl[seg], (uint32_t)(per + 1),
                               __ATOMIC_RELEASE, __HIP_MEMORY_SCOPE_AGENT);
        if (t == 0 && seg > 0) {
            for (int z = 0; z < (1 << 24); ++z) {
                if (__hip_atomic_load(&fl[seg - 1], __ATOMIC_ACQUIRE,
                                      __HIP_MEMORY_SCOPE_AGENT) > (uint32_t)per) break;
                __builtin_amdgcn_s_sleep(1);
            }
        }
        if (t == 1 && seg < SEGS - 1) {
            for (int z = 0; z < (1 << 24); ++z) {
                if (__hip_atomic_load(&fl[seg + 1], __ATOMIC_ACQUIRE,
                                      __HIP_MEMORY_SCOPE_AGENT) > (uint32_t)per) break;
                __builtin_amdgcn_s_sleep(1);
            }
        }
        __syncthreads();
        if (g < 4 && seg > 0) {          // reload low halo from left neighbor
            #pragma unroll
            for (int k = 0; k < RPT; ++k)
                curreg[k] = gload(&gb[(gr0 + k) * WPR + w]);
        }
        if (g >= 12 && seg < SEGS - 1) { // reload high halo from right neighbor
            #pragma unroll
            for (int k = 0; k < RPT; ++k)
                curreg[k] = gload(&gb[(gr0 + k) * WPR + w]);
        }
        __syncthreads();
    }
    if (g >= 4 && g < 12) {
        #pragma unroll
        for (int k = 0; k < RPT; ++k)
            fin[img * IMG_WORDS + (gr0 + k) * WPR + w] = curreg[k];
    }
}

// ---- Kernel 3: bits -> float, tiled 8x -------------------------------------
__global__ __launch_bounds__(256) void k_expand(const uint32_t* __restrict__ mask,
                                                float* __restrict__ out) {
    int t   = blockIdx.x * 256 + threadIdx.x;   // 4,194,304 threads, float4 each
    int img = t >> 16;                          // 65536 float4 per image
    int pix = (t & 65535) << 2;
    uint32_t wv = mask[(img & 7) * IMG_WORDS + (pix >> 5)];
    int sh = pix & 31;
    float4 o;
    o.x = (wv >> (sh + 0)) & 1 ? 1.0f : 0.0f;
    o.y = (wv >> (sh + 1)) & 1 ? 1.0f : 0.0f;
    o.z = (wv >> (sh + 2)) & 1 ? 1.0f : 0.0f;
    o.w = (wv >> (sh + 3)) & 1 ? 1.0f : 0.0f;
    ((float4*)out)[t] = o;
}

extern "C" void kernel_launch(void* const* d_in, const int* in_sizes, int n_in,
                              void* d_out, int out_size, void* d_ws, size_t ws_size,
                              hipStream_t stream) {
    const float* in = (const float*)d_in[0];
    float* out = (float*)d_out;
    uint32_t* flags            = (uint32_t*)d_ws;                      // 64 u32
    unsigned long long* keys   = (unsigned long long*)((char*)d_ws + 4096);
    uint32_t* det              = (uint32_t*)((char*)d_ws + 20480);     // 256 KB
    uint32_t* fin              = (uint32_t*)((char*)d_ws + 282624);    // 256 KB
    uint32_t* gobj             = (uint32_t*)((char*)d_ws + 544768);    // 512 KB

    hipMemsetAsync(flags, 0, 256, stream);      // per-launch flag reset
    k_det   <<<2048,        256, 0, stream>>>(in, det, keys);
    k_grow  <<<NIMG * SEGS, 256, 0, stream>>>(det, keys, fin, gobj, flags);
    k_expand<<<16384,       256, 0, stream>>>(fin, out);
}

// Round 8
// 105.592 us; speedup vs baseline: 1.4810x; 1.4810x over previous
//
#include <hip/hip_runtime.h>
#include <stdint.h>

#define HH 512
#define WW 512
#define NB 8
#define RAD 10
#define NPASS 51
#define WPR 16                 // u32 words per row
#define IMG_WORDS (HH*WPR)     // 8192 words per image
#define STRIDE 540             // words per LDS column: 12 low guard + 512 + 16 high guard
#define GLO 12                 // low guard rows (keeps b128 writes 16B-aligned)
#define RPT 16                 // rows per thread (= one change-tracking group)

// ---- Kernel 1: det bits (x1>x0) + per-BLOCK argmax key (no atomics) --------
__global__ __launch_bounds__(256) void k_det(const float* __restrict__ in,
                                             uint32_t* __restrict__ det,
                                             unsigned long long* __restrict__ keys) {
    __shared__ unsigned long long red[4];
    int tid  = blockIdx.x * 256 + threadIdx.x;
    int lane = threadIdx.x & 63;
    int wv   = threadIdx.x >> 6;
    int wave = tid >> 6;
    long long base = (long long)wave * 256;     // 4 rounds x 64 pixels
    unsigned long long best = 0;
    const float2* in2 = (const float2*)in;
    #pragma unroll
    for (int j = 0; j < 4; ++j) {
        long long p = base + j * 64 + lane;
        float2 v = in2[p];
        // round(softmax_1(v)) == 1  <=>  v.y > v.x   (exact; no expf needed)
        float d = v.y - v.x;
        int pred = (d > 0.0f);
        unsigned long long bits = __ballot(pred);
        if (lane == 0) ((unsigned long long*)det)[wave * 4 + j] = bits;
        // argmax of softmax_1 == argmax of d (sigmoid strictly monotone).
        uint32_t du = __float_as_uint(d);
        uint32_t mono = (du & 0x80000000u) ? ~du : (du | 0x80000000u);
        uint32_t pix = (uint32_t)(p & (HH * WW - 1));
        unsigned long long key = ((unsigned long long)mono << 32)
                               | (unsigned long long)(0xFFFFFFFFu - pix);
        best = key > best ? key : best;
    }
    #pragma unroll
    for (int s = 32; s > 0; s >>= 1) {
        unsigned long long o = __shfl_xor(best, s);
        best = o > best ? o : best;
    }
    if (lane == 0) red[wv] = best;
    __syncthreads();
    if (threadIdx.x == 0) {
        unsigned long long b0 = red[0], b1 = red[1], b2 = red[2], b3 = red[3];
        b0 = b0 > b1 ? b0 : b1;
        b2 = b2 > b3 ? b2 : b3;
        keys[blockIdx.x] = b0 > b2 ? b0 : b2;   // plain store, no atomics
    }
}

// ---- Kernel 2: geodesic dilation + group-granular wave skip ----------------
__global__ __launch_bounds__(512) void k_grow(const uint32_t* __restrict__ det,
                                              const unsigned long long* __restrict__ keys,
                                              uint32_t* __restrict__ outmask) {
    __shared__ __align__(16) uint32_t hb[2][WPR * STRIDE];  // 69 KB, col-major
    __shared__ unsigned long long chg[3];   // mod-3 rotating group-change flags
    __shared__ unsigned long long redk[4];
    int b    = blockIdx.x;
    int t    = threadIdx.x;
    int lane = t & 63;
    int wvid = t >> 6;                   // wave 0..7 (owns rows 64*wvid..+63)
    int w    = t & 15;                   // word-in-row == lane&15 (DPP row!)
    int r0   = (t >> 4) << 4;            // first of 16 rows this thread owns
    uint32_t dreg[RPT];
    const uint32_t* db = det + b * IMG_WORDS;
    #pragma unroll
    for (int k = 0; k < RPT; ++k) dreg[k] = db[(r0 + k) * WPR + w];

    // reduce this image's 256 block keys -> single argmax key
    unsigned long long kk = (t < 256) ? keys[b * 256 + t] : 0ull;
    #pragma unroll
    for (int s = 32; s > 0; s >>= 1) {
        unsigned long long o = __shfl_xor(kk, s);
        kk = o > kk ? o : kk;
    }
    if (lane == 0 && wvid < 4) redk[wvid] = kk;

    for (int i = t; i < 2 * WPR * STRIDE; i += 512) ((uint32_t*)hb)[i] = 0;
    if (t == 0) { chg[0] = 0; chg[1] = 0; chg[2] = 0; }
    __syncthreads();

    unsigned long long key = redk[0];
    key = redk[1] > key ? redk[1] : key;
    key = redk[2] > key ? redk[2] : key;
    key = redk[3] > key ? redk[3] : key;
    uint32_t pix = 0xFFFFFFFFu - (uint32_t)key;
    int sr = pix >> 9, sc = pix & 511;
    uint32_t curreg[RPT];
    #pragma unroll
    for (int k = 0; k < RPT; ++k)        // sparse seed, registers only
        curreg[k] = (sr == r0 + k && (sc >> 5) == w) ? (1u << (sc & 31)) : 0u;

    // wave's skip window: group bits of waves wvid-1(hi 2),wvid(all),wvid+1(lo 2)
    unsigned long long wm = 0xFull << (8 * wvid);
    if (wvid > 0) wm |= 0xCull << (8 * (wvid - 1));
    if (wvid < 7) wm |= 0x3ull << (8 * (wvid + 1));

    uint32_t Dv[RPT];                    // cached H-output (valid while skipping)
    bool bufs_ok = true;
    int a = 0, z = 1, e = 2;             // it%3, (it+1)%3, (it+2)%3==(it-1)%3

    for (int it = 0; it < NPASS; ++it) {
        unsigned long long sk = chg[z];  // G(it-2); barrier-separated from writers
        bool comp = (it < 2) || ((sk & wm) != 0ull);
        uint32_t* colv = &hb[it & 1][w * STRIDE];
        if (comp) {
            // ---- horizontal radius-10: DPP neighbors + u64 log-doubling ----
            #pragma unroll
            for (int k = 0; k < RPT; ++k) {
                uint32_t bb = curreg[k];
                uint32_t aa = (uint32_t)__builtin_amdgcn_update_dpp(
                    0, (int)bb, 0x111, 0xF, 0xF, true);   // word w-1 (0 at w==0)
                uint32_t cc = (uint32_t)__builtin_amdgcn_update_dpp(
                    0, (int)bb, 0x101, 0xF, 0xF, true);   // word w+1 (0 at w==15)
                unsigned long long W = (unsigned long long)(aa >> 22)
                                     | ((unsigned long long)bb << 10)
                                     | ((unsigned long long)cc << 42);
                unsigned long long D = W | (W >> 1);      // [0,1]
                D |= D >> 2;                              // [0,3]
                D |= D >> 4;                              // [0,7]
                unsigned long long D7 = D;
                D |= D >> 8;                              // [0,15]
                D |= D7 >> 13;                            // | [13,20] = [0,20]
                Dv[k] = (uint32_t)D;
            }
            bufs_ok = false;             // only hb[it&1] gets fresh data now
            *(uint4*)&colv[r0 + GLO]      = make_uint4(Dv[0],  Dv[1],  Dv[2],  Dv[3]);
            *(uint4*)&colv[r0 + GLO + 4]  = make_uint4(Dv[4],  Dv[5],  Dv[6],  Dv[7]);
            *(uint4*)&colv[r0 + GLO + 8]  = make_uint4(Dv[8],  Dv[9],  Dv[10], Dv[11]);
            *(uint4*)&colv[r0 + GLO + 12] = make_uint4(Dv[12], Dv[13], Dv[14], Dv[15]);
        } else if (!bufs_ok) {           // first skip after a compute: sync buffer
            *(uint4*)&colv[r0 + GLO]      = make_uint4(Dv[0],  Dv[1],  Dv[2],  Dv[3]);
            *(uint4*)&colv[r0 + GLO + 4]  = make_uint4(Dv[4],  Dv[5],  Dv[6],  Dv[7]);
            *(uint4*)&colv[r0 + GLO + 8]  = make_uint4(Dv[8],  Dv[9],  Dv[10], Dv[11]);
            *(uint4*)&colv[r0 + GLO + 12] = make_uint4(Dv[12], Dv[13], Dv[14], Dv[15]);
            bufs_ok = true;              // both parities now hold current H-output
        }
        __syncthreads();                 // the ONLY barrier per iteration

        if (it >= 1 && chg[e] == 0ull) break;  // G(it-1) empty -> fixed point
        if (t == 0) chg[z] = 0;          // recycle parity for V(it+1)'s writes

        if (comp) {
            // ---- vertical 21-row OR over 36-row window: wide halo reads ----
            uint32_t x[36];              // x[j] = H-out of row (r0-10+j)
            {
                uint2 a0 = *(const uint2*)&colv[r0 + 2];      // rows r0-10,r0-9
                uint4 a1 = *(const uint4*)&colv[r0 + 4];      // rows r0-8..r0-5
                uint4 a2 = *(const uint4*)&colv[r0 + 8];      // rows r0-4..r0-1
                uint4 b0 = *(const uint4*)&colv[r0 + 28];     // rows r0+16..r0+19
                uint4 b1 = *(const uint4*)&colv[r0 + 32];     // rows r0+20..r0+23
                uint2 b2 = *(const uint2*)&colv[r0 + 36];     // rows r0+24,r0+25
                x[0] = a0.x;  x[1] = a0.y;
                x[2] = a1.x;  x[3] = a1.y;  x[4] = a1.z;  x[5] = a1.w;
                x[6] = a2.x;  x[7] = a2.y;  x[8] = a2.z;  x[9] = a2.w;
                #pragma unroll
                for (int k = 0; k < RPT; ++k) x[10 + k] = Dv[k];
                x[26] = b0.x; x[27] = b0.y; x[28] = b0.z; x[29] = b0.w;
                x[30] = b1.x; x[31] = b1.y; x[32] = b1.z; x[33] = b1.w;
                x[34] = b2.x; x[35] = b2.y;
            }
            uint32_t s[21];
            s[20] = x[20];
            #pragma unroll
            for (int i = 19; i >= 0; --i) s[i] = x[i] | s[i + 1];
            uint32_t p[36];
            p[21] = x[21];
            #pragma unroll
            for (int i = 22; i < 36; ++i) p[i] = x[i] | p[i - 1];
            uint32_t diff = 0;
            {
                uint32_t nv = dreg[0] & s[0];
                diff |= nv ^ curreg[0];
                curreg[0] = nv;
            }
            #pragma unroll
            for (int k = 1; k < RPT; ++k) {
                uint32_t nv = dreg[k] & (s[k] | p[k + 20]);
                diff |= nv ^ curreg[k];
                curreg[k] = nv;
            }
            unsigned long long bl = __ballot(diff != 0);
            if (lane == 0) {             // 4 group bits -> this wave's byte
                uint32_t nib = (((bl & 0xFFFFull)        != 0) ? 1u : 0u)
                             | ((((bl >> 16) & 0xFFFFull) != 0) ? 2u : 0u)
                             | ((((bl >> 32) & 0xFFFFull) != 0) ? 4u : 0u)
                             | (((bl >> 48)               != 0) ? 8u : 0u);
                ((uint8_t*)chg)[a * 8 + wvid] = (uint8_t)nib;
            }
        }
        int tmp = a; a = z; z = e; e = tmp;   // rotate mod-3 parities
    }
    #pragma unroll
    for (int k = 0; k < RPT; ++k)
        outmask[b * IMG_WORDS + (r0 + k) * WPR + w] = curreg[k];
}

// ---- Kernel 3: bits -> float, tiled 8x -------------------------------------
__global__ __launch_bounds__(256) void k_expand(const uint32_t* __restrict__ mask,
                                                float* __restrict__ out) {
    int t   = blockIdx.x * 256 + threadIdx.x;   // 4,194,304 threads, float4 each
    int img = t >> 16;                          // 65536 float4 per image
    int pix = (t & 65535) << 2;
    uint32_t wv = mask[(img & 7) * IMG_WORDS + (pix >> 5)];
    int sh = pix & 31;
    float4 o;
    o.x = (wv >> (sh + 0)) & 1 ? 1.0f : 0.0f;
    o.y = (wv >> (sh + 1)) & 1 ? 1.0f : 0.0f;
    o.z = (wv >> (sh + 2)) & 1 ? 1.0f : 0.0f;
    o.w = (wv >> (sh + 3)) & 1 ? 1.0f : 0.0f;
    ((float4*)out)[t] = o;
}

extern "C" void kernel_launch(void* const* d_in, const int* in_sizes, int n_in,
                              void* d_out, int out_size, void* d_ws, size_t ws_size,
                              hipStream_t stream) {
    const float* in = (const float*)d_in[0];
    float* out = (float*)d_out;
    unsigned long long* keys = (unsigned long long*)d_ws;          // 2048 x u64
    uint32_t* det = (uint32_t*)((char*)d_ws + 2048 * 8);
    uint32_t* fin = (uint32_t*)((char*)d_ws + 2048 * 8 + NB * IMG_WORDS * 4);

    k_det   <<<2048,  256, 0, stream>>>(in, det, keys);
    k_grow  <<<NB,    512, 0, stream>>>(det, keys, fin);
    k_expand<<<16384, 256, 0, stream>>>(fin, out);
}